// Round 1
// baseline (297.609 us; speedup 1.0000x reference)
//
#include <hip/hip_runtime.h>

// ---------------------------------------------------------------------------
// MultiHeadSelfAttention: x[2,2048,1024] fp32 -> out[2,2048,1024] fp32
//   qkv = x @ qkv_w^T + qkv_b ; reverse-causal attn (key >= query) ; proj.
// Strategy: bf16 MFMA everywhere (tolerance 2.39e-2 >> bf16 error), fp32 accum.
// ---------------------------------------------------------------------------

#define D_MODEL 1024
#define NHEAD 16
#define HEAD_DIM 64
#define INNER 1024
#define BATCH 2
#define T_SEQ 2048
#define TOKENS (BATCH * T_SEQ)

typedef float f32x4 __attribute__((ext_vector_type(4)));
typedef __bf16 bf16x8 __attribute__((ext_vector_type(8)));
typedef unsigned short u16x8 __attribute__((ext_vector_type(8)));

__device__ __forceinline__ unsigned short f2bf(float f) {
    unsigned int u = __builtin_bit_cast(unsigned int, f);
    u = (u + 0x7FFFu + ((u >> 16) & 1u)) >> 16;   // round-to-nearest-even
    return (unsigned short)u;
}

__device__ __forceinline__ void gload_lds16(const void* g, void* l) {
    __builtin_amdgcn_global_load_lds(
        (const __attribute__((address_space(1))) unsigned int*)g,
        (__attribute__((address_space(3))) unsigned int*)l, 16, 0, 0);
}

// ---------------------------------------------------------------------------
// fp32 -> bf16 convert, float4 vectorized
// ---------------------------------------------------------------------------
__global__ __launch_bounds__(256) void cvt_f32_bf16(
    const float* __restrict__ in, unsigned short* __restrict__ out, int n) {
    int i = (blockIdx.x * 256 + threadIdx.x) * 4;
    if (i < n) {
        float4 v = *reinterpret_cast<const float4*>(in + i);
        ushort4 o;
        o.x = f2bf(v.x); o.y = f2bf(v.y); o.z = f2bf(v.z); o.w = f2bf(v.w);
        *reinterpret_cast<ushort4*>(out + i) = o;
    }
}

// ---------------------------------------------------------------------------
// NT GEMM: C[M][N] = A[M][K] * B[N][K]^T + bias[N]
// m97 structure: 128x128 tile, BK=32, 4 waves (2x2, 64x64 each, 4x4 frags of
// 16x16x32 MFMA), global_load_lds width 16, chunk-swizzled LDS (pre-swizzled
// global source so linear LDS dest stays legal -- rule #21).
// ---------------------------------------------------------------------------
template <int BF16OUT>
__global__ __launch_bounds__(256) void gemm_nt(
    const unsigned short* __restrict__ A,   // [M][K] bf16
    const unsigned short* __restrict__ Bw,  // [N][K] bf16
    const float* __restrict__ bias,         // [N]
    void* __restrict__ Cp, int M, int N, int K) {
    constexpr int BK = 32;
    __shared__ __align__(16) unsigned short Al[128 * BK];
    __shared__ __align__(16) unsigned short Bl[128 * BK];
    const int tid = threadIdx.x;
    const int wid = tid >> 6, lane = tid & 63, lr = lane & 15, lg = lane >> 4;
    const int m0 = blockIdx.y * 128, n0 = blockIdx.x * 128;
    const int wr = wid >> 1, wc = wid & 1;

    f32x4 acc[4][4] = {};

    // staging map: LDS byte = tid*16 + c*4096 -> (row, phys chunk p);
    // logical chunk = p ^ ((row>>1)&3) -> global source column
    int arow[2], acol[2];
#pragma unroll
    for (int c = 0; c < 2; c++) {
        int byte = tid * 16 + c * 4096;
        int row = byte >> 6;
        int p = (byte >> 4) & 3;
        int ch = p ^ ((row >> 1) & 3);
        arow[c] = row;
        acol[c] = ch * 8;
    }

    for (int k0 = 0; k0 < K; k0 += BK) {
#pragma unroll
        for (int c = 0; c < 2; c++) {
            gload_lds16(A + (m0 + arow[c]) * K + k0 + acol[c],
                        (char*)Al + wid * 1024 + c * 4096);
            gload_lds16(Bw + (n0 + arow[c]) * K + k0 + acol[c],
                        (char*)Bl + wid * 1024 + c * 4096);
        }
        __syncthreads();  // drains vmcnt -> LDS tile ready

        const int swz = (lg ^ ((lr >> 1) & 3)) << 4;
        bf16x8 af[4], bf[4];
#pragma unroll
        for (int m = 0; m < 4; m++)
            af[m] = *(const bf16x8*)((char*)Al + (wr * 64 + m * 16 + lr) * 64 + swz);
#pragma unroll
        for (int n = 0; n < 4; n++)
            bf[n] = *(const bf16x8*)((char*)Bl + (wc * 64 + n * 16 + lr) * 64 + swz);
#pragma unroll
        for (int m = 0; m < 4; m++)
#pragma unroll
            for (int n = 0; n < 4; n++)
                acc[m][n] = __builtin_amdgcn_mfma_f32_16x16x32_bf16(
                    af[m], bf[n], acc[m][n], 0, 0, 0);
        __syncthreads();  // all reads done before next overwrite
    }

    // epilogue: C/D layout row=(l>>4)*4+i, col=l&15  [m89-verified]
#pragma unroll
    for (int n = 0; n < 4; n++) {
        const int col = n0 + wc * 64 + n * 16 + lr;
        const float bv = bias[col];
#pragma unroll
        for (int m = 0; m < 4; m++) {
            const int row = m0 + wr * 64 + m * 16 + lg * 4;
#pragma unroll
            for (int i = 0; i < 4; i++) {
                float v = acc[m][n][i] + bv;
                if (BF16OUT)
                    ((unsigned short*)Cp)[(long)(row + i) * N + col] = f2bf(v);
                else
                    ((float*)Cp)[(long)(row + i) * N + col] = v;
            }
        }
    }
}

// ---------------------------------------------------------------------------
// Flash attention, reverse-causal (keep key >= query).
// Block: 256 thr / 4 waves; wave w owns 16 queries. QB=64 queries per block,
// KB=64 keys per tile, k-loop from kt=qt (all earlier keys masked out anyway).
// K LDS [64][64] row-swizzled; V LDS transposed [d][k] row-swizzled;
// P repacked through per-wave LDS into MFMA A-frag layout.
// ---------------------------------------------------------------------------
__global__ __launch_bounds__(256) void attn_fwd(
    const unsigned short* __restrict__ qkv,  // [TOKENS][3*INNER] bf16
    unsigned short* __restrict__ aout)       // [TOKENS][INNER] bf16
{
    constexpr int KB = 64;
    __shared__ __align__(16) unsigned short Kl[KB * 64];   // [k][d] swizzled
    __shared__ __align__(16) unsigned short Vt[64 * KB];   // [d][k] swizzled
    __shared__ __align__(16) unsigned short Pl[4][16 * KB];

    const int tid = threadIdx.x;
    const int wid = tid >> 6, lane = tid & 63, lr = lane & 15, lg = lane >> 4;
    const int qt = blockIdx.x * 64;
    const int b = blockIdx.y >> 4, h = blockIdx.y & 15;
    const float cexp = 0.18033688011112042f;  // log2(e) / sqrt(HEAD_DIM)

    // Q fragments (A-layout: row=l&15, k=(l>>4)*8+i), held in registers
    const unsigned short* qbase =
        qkv + (b * T_SEQ + qt + wid * 16 + lr) * (3 * INNER) + h * HEAD_DIM;
    const bf16x8 qf0 = *(const bf16x8*)(qbase + lg * 8);
    const bf16x8 qf1 = *(const bf16x8*)(qbase + 32 + lg * 8);

    float mrun[4], lsum[4];
    f32x4 accO[4] = {};
#pragma unroll
    for (int i = 0; i < 4; i++) { mrun[i] = -1e30f; lsum[i] = 0.f; }

    for (int kt = qt; kt < T_SEQ; kt += KB) {
        if (kt > qt) __syncthreads();  // prior tile's LDS reads complete

        // ---- stage K (vector) and V (transposed, scalar writes) ----
#pragma unroll
        for (int p = 0; p < 2; p++) {
            const int idx = p * 256 + tid;
            const int r = idx >> 3, cs = idx & 7;
            const unsigned short* kr =
                qkv + (b * T_SEQ + kt + r) * (3 * INNER) + INNER + h * HEAD_DIM + cs * 8;
            u16x8 kv = *(const u16x8*)kr;
            *(u16x8*)((char*)Kl + r * 128 +
                      ((cs * 16) ^ ((((r) ^ (r >> 3)) & 7) << 4))) = kv;
            u16x8 vv = *(const u16x8*)(kr + INNER);
#pragma unroll
            for (int j = 0; j < 8; j++) {
                const int d = cs * 8 + j;
                *(unsigned short*)((char*)Vt + d * 128 +
                                   ((r * 2) ^ (((d ^ (d >> 3)) & 7) << 4))) = vv[j];
            }
        }
        __syncthreads();

        // ---- S = Q K^T (raw, scale folded into exp) ----
        f32x4 s[4];
#pragma unroll
        for (int f = 0; f < 4; f++) {
            const int r = f * 16 + lr;
            const int sw = (((r) ^ (r >> 3)) & 7) << 4;
            bf16x8 k0 = *(const bf16x8*)((char*)Kl + r * 128 + ((lg * 16) ^ sw));
            bf16x8 k1 = *(const bf16x8*)((char*)Kl + r * 128 + ((64 + lg * 16) ^ sw));
            f32x4 z = {0.f, 0.f, 0.f, 0.f};
            z = __builtin_amdgcn_mfma_f32_16x16x32_bf16(qf0, k0, z, 0, 0, 0);
            s[f] = __builtin_amdgcn_mfma_f32_16x16x32_bf16(qf1, k1, z, 0, 0, 0);
        }

        // reverse-causal mask: only first tile can violate key>=query
        if (kt == qt) {
#pragma unroll
            for (int f = 0; f < 4; f++)
#pragma unroll
                for (int i = 0; i < 4; i++) {
                    const int kg = f * 16 + lr;            // within tile == global-qt
                    const int qg = wid * 16 + lg * 4 + i;  // within block
                    if (kg < qg) s[f][i] = -1e30f;
                }
        }

        // ---- online softmax (rows live in 16-lane groups) ----
        float pv[4][4];
#pragma unroll
        for (int i = 0; i < 4; i++) {
            float v = fmaxf(fmaxf(s[0][i], s[1][i]), fmaxf(s[2][i], s[3][i]));
            v = fmaxf(v, __shfl_xor(v, 1));
            v = fmaxf(v, __shfl_xor(v, 2));
            v = fmaxf(v, __shfl_xor(v, 4));
            v = fmaxf(v, __shfl_xor(v, 8));
            const float mnew = fmaxf(mrun[i], v);
            const float alpha = exp2f((mrun[i] - mnew) * cexp);
            float rs = 0.f;
#pragma unroll
            for (int f = 0; f < 4; f++) {
                const float p = exp2f((s[f][i] - mnew) * cexp);
                pv[f][i] = p;
                rs += p;
            }
            rs += __shfl_xor(rs, 1);
            rs += __shfl_xor(rs, 2);
            rs += __shfl_xor(rs, 4);
            rs += __shfl_xor(rs, 8);
            lsum[i] = lsum[i] * alpha + rs;
            mrun[i] = mnew;
#pragma unroll
            for (int d = 0; d < 4; d++) accO[d][i] *= alpha;
        }

        // ---- P -> per-wave LDS (swizzled), then read back in A-frag layout ----
#pragma unroll
        for (int i = 0; i < 4; i++) {
            const int q = lg * 4 + i;
            const int swp = ((q ^ (q >> 3)) & 7) << 4;
#pragma unroll
            for (int f = 0; f < 4; f++)
                *(unsigned short*)((char*)Pl[wid] + q * 128 +
                                   (((f * 16 + lr) * 2) ^ swp)) = f2bf(pv[f][i]);
        }
        asm volatile("s_waitcnt lgkmcnt(0)" ::: "memory");  // wave-internal W->R

        // ---- O += P V ----
        const int swa = ((lr ^ (lr >> 3)) & 7) << 4;
#pragma unroll
        for (int ks = 0; ks < 2; ks++) {
            bf16x8 a = *(const bf16x8*)((char*)Pl[wid] + lr * 128 +
                                        ((ks * 64 + lg * 16) ^ swa));
#pragma unroll
            for (int df = 0; df < 4; df++) {
                const int d = df * 16 + lr;
                const int swv = ((d ^ (d >> 3)) & 7) << 4;
                bf16x8 bv = *(const bf16x8*)((char*)Vt + d * 128 +
                                             ((ks * 64 + lg * 16) ^ swv));
                accO[df] = __builtin_amdgcn_mfma_f32_16x16x32_bf16(a, bv, accO[df], 0, 0, 0);
            }
        }
    }

    // ---- normalize + store (bf16) ----
#pragma unroll
    for (int df = 0; df < 4; df++)
#pragma unroll
        for (int i = 0; i < 4; i++) {
            const int row = b * T_SEQ + qt + wid * 16 + lg * 4 + i;
            aout[row * INNER + h * HEAD_DIM + df * 16 + lr] =
                f2bf(accO[df][i] / lsum[i]);
        }
}

// ---------------------------------------------------------------------------
extern "C" void kernel_launch(void* const* d_in, const int* in_sizes, int n_in,
                              void* d_out, int out_size, void* d_ws, size_t ws_size,
                              hipStream_t stream) {
    const float* x     = (const float*)d_in[0];
    const float* qkv_w = (const float*)d_in[1];
    const float* qkv_b = (const float*)d_in[2];
    const float* out_w = (const float*)d_in[3];
    const float* out_b = (const float*)d_in[4];
    float* out = (float*)d_out;

    // workspace layout (48 MB total)
    char* ws = (char*)d_ws;
    unsigned short* xb   = (unsigned short*)(ws);                  //  8 MB x bf16
    unsigned short* wqb  = (unsigned short*)(ws + (8l << 20));     //  6 MB qkv_w bf16
    unsigned short* wob  = (unsigned short*)(ws + (14l << 20));    //  2 MB out_w bf16
    unsigned short* qkvb = (unsigned short*)(ws + (16l << 20));    // 24 MB qkv bf16
    unsigned short* aob  = (unsigned short*)(ws + (40l << 20));    //  8 MB attn out bf16

    cvt_f32_bf16<<<4096, 256, 0, stream>>>(x, xb, TOKENS * D_MODEL);
    cvt_f32_bf16<<<3072, 256, 0, stream>>>(qkv_w, wqb, 3 * INNER * D_MODEL);
    cvt_f32_bf16<<<1024, 256, 0, stream>>>(out_w, wob, D_MODEL * INNER);

    gemm_nt<1><<<dim3(3 * INNER / 128, TOKENS / 128), 256, 0, stream>>>(
        xb, wqb, qkv_b, qkvb, TOKENS, 3 * INNER, D_MODEL);

    attn_fwd<<<dim3(T_SEQ / 64, BATCH * NHEAD), 256, 0, stream>>>(qkvb, aob);

    gemm_nt<0><<<dim3(D_MODEL / 128, TOKENS / 128), 256, 0, stream>>>(
        aob, wob, out_b, out, TOKENS, D_MODEL, INNER);
}

// Round 3
// 287.776 us; speedup vs baseline: 1.0342x; 1.0342x over previous
//
#include <hip/hip_runtime.h>

// ---------------------------------------------------------------------------
// MultiHeadSelfAttention: x[2,2048,1024] fp32 -> out[2,2048,1024] fp32
//   qkv = x @ qkv_w^T + qkv_b ; reverse-causal attn (key >= query) ; proj.
// bf16 MFMA everywhere (tol 2.39e-2 >> bf16 err), fp32 accum.
// ---------------------------------------------------------------------------

#define D_MODEL 1024
#define NHEAD 16
#define HEAD_DIM 64
#define INNER 1024
#define BATCH 2
#define T_SEQ 2048
#define TOKENS (BATCH * T_SEQ)

typedef float f32x4 __attribute__((ext_vector_type(4)));
typedef __bf16 bf16x8 __attribute__((ext_vector_type(8)));
typedef __bf16 bf16x4 __attribute__((ext_vector_type(4)));
typedef unsigned short u16x8 __attribute__((ext_vector_type(8)));

__device__ __forceinline__ unsigned short f2bf(float f) {
    unsigned int u = __builtin_bit_cast(unsigned int, f);
    u = (u + 0x7FFFu + ((u >> 16) & 1u)) >> 16;   // round-to-nearest-even
    return (unsigned short)u;
}

__device__ __forceinline__ void gload_lds16(const void* g, void* l) {
    __builtin_amdgcn_global_load_lds(
        (const __attribute__((address_space(1))) unsigned int*)g,
        (__attribute__((address_space(3))) unsigned int*)l, 16, 0, 0);
}

__device__ __forceinline__ unsigned ldsa(const void* p) {
    return (unsigned)(unsigned long long)(const __attribute__((address_space(3))) void*)p;
}

// Fused wait+barrier as ONE volatile asm with memory clobber: compiler cannot
// move LDS ops across it (s_barrier builtin alone is NOT a memory fence --
// that was R2's race), and vmcnt is NOT drained (prefetch stays in flight).
__device__ __forceinline__ void lds_barrier() {
    asm volatile("s_waitcnt lgkmcnt(0)\n\ts_barrier" ::: "memory");
}

// tr read: lane gets column ((addr%128)/8) of the 128B-aligned 4x16 bf16 block;
// offset:128 = next subtile (next 4 k's). Early-clobber: outputs must not
// alias the address input (ds_read writes async).
__device__ __forceinline__ void tr_read2(unsigned addr, bf16x4& a, bf16x4& b) {
    asm volatile("ds_read_b64_tr_b16 %0, %2 offset:0\n\t"
                 "ds_read_b64_tr_b16 %1, %2 offset:128"
                 : "=&v"(a), "=&v"(b) : "v"(addr));
}

// ---------------------------------------------------------------------------
__global__ __launch_bounds__(256) void cvt_f32_bf16(
    const float* __restrict__ in, unsigned short* __restrict__ out, int n) {
    int i = (blockIdx.x * 256 + threadIdx.x) * 4;
    if (i < n) {
        float4 v = *reinterpret_cast<const float4*>(in + i);
        ushort4 o;
        o.x = f2bf(v.x); o.y = f2bf(v.y); o.z = f2bf(v.z); o.w = f2bf(v.w);
        *reinterpret_cast<ushort4*>(out + i) = o;
    }
}

// ---------------------------------------------------------------------------
// NT GEMM (m97 structure) -- unchanged (tripwire-proven in R1).
// ---------------------------------------------------------------------------
template <int BF16OUT>
__global__ __launch_bounds__(256) void gemm_nt(
    const unsigned short* __restrict__ A,   // [M][K] bf16
    const unsigned short* __restrict__ Bw,  // [N][K] bf16
    const float* __restrict__ bias,         // [N]
    void* __restrict__ Cp, int M, int N, int K) {
    constexpr int BK = 32;
    __shared__ __align__(16) unsigned short Al[128 * BK];
    __shared__ __align__(16) unsigned short Bl[128 * BK];
    const int tid = threadIdx.x;
    const int wid = tid >> 6, lane = tid & 63, lr = lane & 15, lg = lane >> 4;
    const int m0 = blockIdx.y * 128, n0 = blockIdx.x * 128;
    const int wr = wid >> 1, wc = wid & 1;

    f32x4 acc[4][4] = {};

    int arow[2], acol[2];
#pragma unroll
    for (int c = 0; c < 2; c++) {
        int byte = tid * 16 + c * 4096;
        int row = byte >> 6;
        int p = (byte >> 4) & 3;
        int ch = p ^ ((row >> 1) & 3);
        arow[c] = row;
        acol[c] = ch * 8;
    }

    for (int k0 = 0; k0 < K; k0 += BK) {
#pragma unroll
        for (int c = 0; c < 2; c++) {
            gload_lds16(A + (m0 + arow[c]) * K + k0 + acol[c],
                        (char*)Al + wid * 1024 + c * 4096);
            gload_lds16(Bw + (n0 + arow[c]) * K + k0 + acol[c],
                        (char*)Bl + wid * 1024 + c * 4096);
        }
        __syncthreads();

        const int swz = (lg ^ ((lr >> 1) & 3)) << 4;
        bf16x8 af[4], bfr[4];
#pragma unroll
        for (int m = 0; m < 4; m++)
            af[m] = *(const bf16x8*)((char*)Al + (wr * 64 + m * 16 + lr) * 64 + swz);
#pragma unroll
        for (int n = 0; n < 4; n++)
            bfr[n] = *(const bf16x8*)((char*)Bl + (wc * 64 + n * 16 + lr) * 64 + swz);
#pragma unroll
        for (int m = 0; m < 4; m++)
#pragma unroll
            for (int n = 0; n < 4; n++)
                acc[m][n] = __builtin_amdgcn_mfma_f32_16x16x32_bf16(
                    af[m], bfr[n], acc[m][n], 0, 0, 0);
        __syncthreads();
    }

#pragma unroll
    for (int n = 0; n < 4; n++) {
        const int col = n0 + wc * 64 + n * 16 + lr;
        const float bv = bias[col];
#pragma unroll
        for (int m = 0; m < 4; m++) {
            const int row = m0 + wr * 64 + m * 16 + lg * 4;
#pragma unroll
            for (int i = 0; i < 4; i++) {
                float v = acc[m][n][i] + bv;
                if (BF16OUT)
                    ((unsigned short*)Cp)[(long)(row + i) * N + col] = f2bf(v);
                else
                    ((float*)Cp)[(long)(row + i) * N + col] = v;
            }
        }
    }
}

// ---------------------------------------------------------------------------
// Flash attention, reverse-causal (keep key >= query).
// 256 thr / 4 waves; wave owns 16 queries; KB=64 key tile.
// Pipeline: reg-prefetch next K/V tile; LDS double-buffered; one fused
// lgkmcnt+s_barrier per tile (memory-clobbered, no vmcnt drain).
// K LDS [k][64] XOR-row-swizzled; V LDS tr-subtiled [d0][k0][4][16] consumed
// via ds_read_b64_tr_b16; P via per-wave swizzled LDS; defer-max (THR=64 raw).
// ---------------------------------------------------------------------------
__global__ __launch_bounds__(256) void attn_fwd(
    const unsigned short* __restrict__ qkv,  // [TOKENS][3*INNER] bf16
    unsigned short* __restrict__ aout)       // [TOKENS][INNER] bf16
{
    constexpr int KB = 64;
    __shared__ __align__(16) unsigned short Kl[2][KB * 64];   // 8 KB x2
    __shared__ __align__(16) unsigned short Vs[2][KB * 64];   // 8 KB x2
    __shared__ __align__(16) unsigned short Pl[4][16 * KB];   // 8 KB

    const int tid = threadIdx.x;
    const int wid = tid >> 6, lane = tid & 63, lr = lane & 15, lg = lane >> 4;
    const int qt = blockIdx.x * 64;
    const int b = blockIdx.y >> 4, h = blockIdx.y & 15;
    const float cexp = 0.18033688011112042f;  // log2(e)/sqrt(64)

    // Q fragments (A-layout: row=l&15, k=(l>>4)*8+j)
    const unsigned short* qbase =
        qkv + (size_t)(b * T_SEQ + qt + wid * 16 + lr) * 3072 + h * HEAD_DIM;
    const bf16x8 qf0 = *(const bf16x8*)(qbase + lg * 8);
    const bf16x8 qf1 = *(const bf16x8*)(qbase + 32 + lg * 8);

    // staging maps: idx = p*256+tid -> row r, 8-elem chunk cs
    int kwo[2], vwo[2];
    const unsigned short* gk[2];
#pragma unroll
    for (int p = 0; p < 2; p++) {
        const int idx = p * 256 + tid;
        const int r = idx >> 3, cs = idx & 7;
        kwo[p] = r * 128 + ((cs * 16) ^ (((r ^ (r >> 3)) & 7) << 4));
        vwo[p] = (cs >> 1) * 2048 + (r >> 2) * 128 + (r & 3) * 32 + (cs & 1) * 16;
        gk[p] = qkv + (size_t)(b * T_SEQ + qt + r) * 3072 + INNER + h * HEAD_DIM + cs * 8;
    }

    // prologue: load first tile into regs
    u16x8 kreg[2], vreg[2];
#pragma unroll
    for (int p = 0; p < 2; p++) {
        kreg[p] = *(const u16x8*)gk[p];
        vreg[p] = *(const u16x8*)(gk[p] + INNER);
        gk[p] += KB * 3072;
    }

    float mrun[4], lsum[4];
    f32x4 accO[4] = {};
#pragma unroll
    for (int i = 0; i < 4; i++) { mrun[i] = -1e30f; lsum[i] = 0.f; }

    int buf = 0;
    for (int kt = qt; kt < T_SEQ; kt += KB) {
        // ---- write staged regs -> LDS[buf]; issue next tile's loads ----
#pragma unroll
        for (int p = 0; p < 2; p++) {
            *(u16x8*)((char*)Kl[buf] + kwo[p]) = kreg[p];
            *(u16x8*)((char*)Vs[buf] + vwo[p]) = vreg[p];
        }
        if (kt + KB < T_SEQ) {
#pragma unroll
            for (int p = 0; p < 2; p++) {
                kreg[p] = *(const u16x8*)gk[p];
                vreg[p] = *(const u16x8*)(gk[p] + INNER);
                gk[p] += KB * 3072;
            }
        }
        lds_barrier();  // fused lgkmcnt(0)+s_barrier, memory clobber, no vmcnt drain

        // ---- S = Q K^T ----
        f32x4 s[4];
#pragma unroll
        for (int f = 0; f < 4; f++) {
            const int r = f * 16 + lr;
            const int sw = ((r ^ (r >> 3)) & 7) << 4;
            bf16x8 k0 = *(const bf16x8*)((char*)Kl[buf] + r * 128 + ((lg * 16) ^ sw));
            bf16x8 k1 = *(const bf16x8*)((char*)Kl[buf] + r * 128 + ((64 + lg * 16) ^ sw));
            f32x4 z = {0.f, 0.f, 0.f, 0.f};
            z = __builtin_amdgcn_mfma_f32_16x16x32_bf16(qf0, k0, z, 0, 0, 0);
            s[f] = __builtin_amdgcn_mfma_f32_16x16x32_bf16(qf1, k1, z, 0, 0, 0);
        }

        if (kt == qt) {  // reverse-causal: only diag tile can violate key>=query
#pragma unroll
            for (int f = 0; f < 4; f++)
#pragma unroll
                for (int i = 0; i < 4; i++) {
                    const int kg = f * 16 + lr;
                    const int qg = wid * 16 + lg * 4 + i;
                    if (kg < qg) s[f][i] = -1e30f;
                }
        }

        // ---- online softmax with defer-max (T13) ----
        float vmax[4];
#pragma unroll
        for (int i = 0; i < 4; i++) {
            float v = fmaxf(fmaxf(s[0][i], s[1][i]), fmaxf(s[2][i], s[3][i]));
            v = fmaxf(v, __shfl_xor(v, 1));
            v = fmaxf(v, __shfl_xor(v, 2));
            v = fmaxf(v, __shfl_xor(v, 4));
            v = fmaxf(v, __shfl_xor(v, 8));
            vmax[i] = v;
        }
        int need = 0;
#pragma unroll
        for (int i = 0; i < 4; i++) need |= (vmax[i] > mrun[i] + 64.f);
        if (__any(need)) {
#pragma unroll
            for (int i = 0; i < 4; i++) {
                const float mnew = fmaxf(mrun[i], vmax[i]);
                const float alpha = exp2f((mrun[i] - mnew) * cexp);
                lsum[i] *= alpha;
#pragma unroll
                for (int d = 0; d < 4; d++) accO[d][i] *= alpha;
                mrun[i] = mnew;
            }
        }
#pragma unroll
        for (int i = 0; i < 4; i++) {
            const int q = lg * 4 + i;
            const int swp = ((q ^ (q >> 3)) & 7) << 4;
            float rs = 0.f;
#pragma unroll
            for (int f = 0; f < 4; f++) {
                const float pp = exp2f((s[f][i] - mrun[i]) * cexp);
                rs += pp;
                *(unsigned short*)((char*)Pl[wid] + q * 128 +
                                   (((f * 16 + lr) * 2) ^ swp)) = f2bf(pp);
            }
            rs += __shfl_xor(rs, 1);
            rs += __shfl_xor(rs, 2);
            rs += __shfl_xor(rs, 4);
            rs += __shfl_xor(rs, 8);
            lsum[i] += rs;
        }

        // ---- O += P V  (V via hardware transpose reads) ----
        const int swa = ((lr ^ (lr >> 3)) & 7) << 4;
        const unsigned vsb = ldsa(Vs[buf]) + lr * 8;
#pragma unroll
        for (int ks = 0; ks < 2; ks++) {
            bf16x8 pa = *(const bf16x8*)((char*)Pl[wid] + lr * 128 +
                                         ((ks * 64 + lg * 16) ^ swa));
            bf16x4 t0[4], t1[4];
#pragma unroll
            for (int df = 0; df < 4; df++)
                tr_read2(vsb + df * 2048 + (ks * 8 + lg * 2) * 128, t0[df], t1[df]);
            asm volatile("s_waitcnt lgkmcnt(0)" ::: "memory");
            __builtin_amdgcn_sched_barrier(0);  // rule #18: don't hoist MFMA
#pragma unroll
            for (int df = 0; df < 4; df++) {
                bf16x8 bv = __builtin_shufflevector(t0[df], t1[df],
                                                    0, 1, 2, 3, 4, 5, 6, 7);
                accO[df] = __builtin_amdgcn_mfma_f32_16x16x32_bf16(
                    pa, bv, accO[df], 0, 0, 0);
            }
        }
        buf ^= 1;
    }

    // ---- normalize + store ----
#pragma unroll
    for (int df = 0; df < 4; df++)
#pragma unroll
        for (int i = 0; i < 4; i++) {
            const int row = b * T_SEQ + qt + wid * 16 + lg * 4 + i;
            aout[(size_t)row * INNER + h * HEAD_DIM + df * 16 + lr] =
                f2bf(accO[df][i] / lsum[i]);
        }
}

// ---------------------------------------------------------------------------
extern "C" void kernel_launch(void* const* d_in, const int* in_sizes, int n_in,
                              void* d_out, int out_size, void* d_ws, size_t ws_size,
                              hipStream_t stream) {
    const float* x     = (const float*)d_in[0];
    const float* qkv_w = (const float*)d_in[1];
    const float* qkv_b = (const float*)d_in[2];
    const float* out_w = (const float*)d_in[3];
    const float* out_b = (const float*)d_in[4];
    float* out = (float*)d_out;

    char* ws = (char*)d_ws;
    unsigned short* xb   = (unsigned short*)(ws);                  //  8 MB
    unsigned short* wqb  = (unsigned short*)(ws + (8l << 20));     //  6 MB
    unsigned short* wob  = (unsigned short*)(ws + (14l << 20));    //  2 MB
    unsigned short* qkvb = (unsigned short*)(ws + (16l << 20));    // 24 MB
    unsigned short* aob  = (unsigned short*)(ws + (40l << 20));    //  8 MB

    cvt_f32_bf16<<<4096, 256, 0, stream>>>(x, xb, TOKENS * D_MODEL);
    cvt_f32_bf16<<<3072, 256, 0, stream>>>(qkv_w, wqb, 3 * INNER * D_MODEL);
    cvt_f32_bf16<<<1024, 256, 0, stream>>>(out_w, wob, D_MODEL * INNER);

    gemm_nt<1><<<dim3(3 * INNER / 128, TOKENS / 128), 256, 0, stream>>>(
        xb, wqb, qkv_b, qkvb, TOKENS, 3 * INNER, D_MODEL);

    attn_fwd<<<dim3(T_SEQ / 64, BATCH * NHEAD), 256, 0, stream>>>(qkvb, aob);

    gemm_nt<0><<<dim3(D_MODEL / 128, TOKENS / 128), 256, 0, stream>>>(
        aob, wob, out_b, out, TOKENS, D_MODEL, INNER);
}

// Round 4
// 206.585 us; speedup vs baseline: 1.4406x; 1.3930x over previous
//
#include <hip/hip_runtime.h>

// ---------------------------------------------------------------------------
// MultiHeadSelfAttention: x[2,2048,1024] fp32 -> out[2,2048,1024] fp32
//   qkv = x @ qkv_w^T + qkv_b ; reverse-causal attn (key >= query) ; proj.
// bf16 MFMA everywhere (tol 2.39e-2 >> bf16 err), fp32 accum.
// ---------------------------------------------------------------------------

#define D_MODEL 1024
#define NHEAD 16
#define HEAD_DIM 64
#define INNER 1024
#define BATCH 2
#define T_SEQ 2048
#define TOKENS (BATCH * T_SEQ)

typedef float f32x4 __attribute__((ext_vector_type(4)));
typedef __bf16 bf16x8 __attribute__((ext_vector_type(8)));
typedef __bf16 bf16x4 __attribute__((ext_vector_type(4)));
typedef unsigned short u16x8 __attribute__((ext_vector_type(8)));
typedef unsigned int u32x2 __attribute__((ext_vector_type(2)));

__device__ __forceinline__ unsigned short f2bf(float f) {
    unsigned int u = __builtin_bit_cast(unsigned int, f);
    u = (u + 0x7FFFu + ((u >> 16) & 1u)) >> 16;   // round-to-nearest-even
    return (unsigned short)u;
}

__device__ __forceinline__ unsigned int cvt_pk_bf16(float lo, float hi) {
    unsigned int r;
    asm("v_cvt_pk_bf16_f32 %0, %1, %2" : "=v"(r) : "v"(lo), "v"(hi));
    return r;
}

__device__ __forceinline__ void gload_lds16(const void* g, void* l) {
    __builtin_amdgcn_global_load_lds(
        (const __attribute__((address_space(1))) unsigned int*)g,
        (__attribute__((address_space(3))) unsigned int*)l, 16, 0, 0);
}

__device__ __forceinline__ unsigned ldsa(const void* p) {
    return (unsigned)(unsigned long long)(const __attribute__((address_space(3))) void*)p;
}

// Fused wait+barrier: ONE volatile asm w/ memory clobber (compiler cannot move
// LDS ops across), vmcnt NOT drained (global prefetch stays in flight).
__device__ __forceinline__ void lds_barrier() {
    asm volatile("s_waitcnt lgkmcnt(0)\n\ts_barrier" ::: "memory");
}

__device__ __forceinline__ void tr_read2(unsigned addr, bf16x4& a, bf16x4& b) {
    asm volatile("ds_read_b64_tr_b16 %0, %2 offset:0\n\t"
                 "ds_read_b64_tr_b16 %1, %2 offset:128"
                 : "=&v"(a), "=&v"(b) : "v"(addr));
}

// ---------------------------------------------------------------------------
__global__ __launch_bounds__(256) void cvt_f32_bf16(
    const float* __restrict__ in, unsigned short* __restrict__ out, int n) {
    int i = (blockIdx.x * 256 + threadIdx.x) * 4;
    if (i < n) {
        float4 v = *reinterpret_cast<const float4*>(in + i);
        ushort4 o;
        o.x = f2bf(v.x); o.y = f2bf(v.y); o.z = f2bf(v.z); o.w = f2bf(v.w);
        *reinterpret_cast<ushort4*>(out + i) = o;
    }
}

// ---------------------------------------------------------------------------
// NT GEMM (m97 structure) -- unchanged (proven R1/R3).
// ---------------------------------------------------------------------------
template <int BF16OUT>
__global__ __launch_bounds__(256) void gemm_nt(
    const unsigned short* __restrict__ A,   // [M][K] bf16
    const unsigned short* __restrict__ Bw,  // [N][K] bf16
    const float* __restrict__ bias,         // [N]
    void* __restrict__ Cp, int M, int N, int K) {
    constexpr int BK = 32;
    __shared__ __align__(16) unsigned short Al[128 * BK];
    __shared__ __align__(16) unsigned short Bl[128 * BK];
    const int tid = threadIdx.x;
    const int wid = tid >> 6, lane = tid & 63, lr = lane & 15, lg = lane >> 4;
    const int m0 = blockIdx.y * 128, n0 = blockIdx.x * 128;
    const int wr = wid >> 1, wc = wid & 1;

    f32x4 acc[4][4] = {};

    int arow[2], acol[2];
#pragma unroll
    for (int c = 0; c < 2; c++) {
        int byte = tid * 16 + c * 4096;
        int row = byte >> 6;
        int p = (byte >> 4) & 3;
        int ch = p ^ ((row >> 1) & 3);
        arow[c] = row;
        acol[c] = ch * 8;
    }

    for (int k0 = 0; k0 < K; k0 += BK) {
#pragma unroll
        for (int c = 0; c < 2; c++) {
            gload_lds16(A + (m0 + arow[c]) * K + k0 + acol[c],
                        (char*)Al + wid * 1024 + c * 4096);
            gload_lds16(Bw + (n0 + arow[c]) * K + k0 + acol[c],
                        (char*)Bl + wid * 1024 + c * 4096);
        }
        __syncthreads();

        const int swz = (lg ^ ((lr >> 1) & 3)) << 4;
        bf16x8 af[4], bfr[4];
#pragma unroll
        for (int m = 0; m < 4; m++)
            af[m] = *(const bf16x8*)((char*)Al + (wr * 64 + m * 16 + lr) * 64 + swz);
#pragma unroll
        for (int n = 0; n < 4; n++)
            bfr[n] = *(const bf16x8*)((char*)Bl + (wc * 64 + n * 16 + lr) * 64 + swz);
#pragma unroll
        for (int m = 0; m < 4; m++)
#pragma unroll
            for (int n = 0; n < 4; n++)
                acc[m][n] = __builtin_amdgcn_mfma_f32_16x16x32_bf16(
                    af[m], bfr[n], acc[m][n], 0, 0, 0);
        __syncthreads();
    }

#pragma unroll
    for (int n = 0; n < 4; n++) {
        const int col = n0 + wc * 64 + n * 16 + lr;
        const float bv = bias[col];
#pragma unroll
        for (int m = 0; m < 4; m++) {
            const int row = m0 + wr * 64 + m * 16 + lg * 4;
#pragma unroll
            for (int i = 0; i < 4; i++) {
                float v = acc[m][n][i] + bv;
                if (BF16OUT)
                    ((unsigned short*)Cp)[(long)(row + i) * N + col] = f2bf(v);
                else
                    ((float*)Cp)[(long)(row + i) * N + col] = v;
            }
        }
    }
}

// ---------------------------------------------------------------------------
// Flash attention, reverse-causal (keep key >= query).
// Balance: block = q-tile pair {p, 31-p} run sequentially -> 33 tiles/block
// uniformly; 512 blocks, 2/CU, no tail.
// Swapped QK^T: S^T = mfma(K, Q) -> lane holds 16 scores of ONE query (l&15);
// softmax is in-lane + 2 shfl; P packed via v_cvt_pk_bf16_f32 -> 4 vector
// ds_write_b64 (swizzled). PV (tr_read V) + epilogue unchanged from R3.
// ---------------------------------------------------------------------------
__global__ __launch_bounds__(256) void attn_fwd(
    const unsigned short* __restrict__ qkv,  // [TOKENS][3*INNER] bf16
    unsigned short* __restrict__ aout)       // [TOKENS][INNER] bf16
{
    constexpr int KB = 64;
    __shared__ __align__(16) unsigned short Kl[2][KB * 64];   // 8 KB x2
    __shared__ __align__(16) unsigned short Vs[2][KB * 64];   // 8 KB x2
    __shared__ __align__(16) unsigned short Pl[4][16 * KB];   // 8 KB

    const int tid = threadIdx.x;
    const int wid = tid >> 6, lane = tid & 63, lr = lane & 15, lg = lane >> 4;
    const int pq = blockIdx.x;                  // pair index 0..15
    const int b = blockIdx.y >> 4, h = blockIdx.y & 15;
    const float cexp = 0.18033688011112042f;    // log2(e)/sqrt(64)
    const int qA = pq * 64, qB = (31 - pq) * 64;

    // staging maps: idx = p*256+tid -> row r (0..63), 8-elem chunk cs (0..7)
    int kwo[2], vwo[2], roff[2], cs8[2];
#pragma unroll
    for (int p = 0; p < 2; p++) {
        const int idx = p * 256 + tid;
        const int r = idx >> 3, cs = idx & 7;
        kwo[p] = r * 128 + ((cs * 16) ^ (((r ^ (r >> 3)) & 7) << 4));
        vwo[p] = (cs >> 1) * 2048 + (r >> 2) * 128 + (r & 3) * 32 + (cs & 1) * 16;
        roff[p] = r;
        cs8[p] = cs * 8;
    }
    const unsigned short* kvb =
        qkv + (size_t)b * T_SEQ * 3072 + INNER + h * HEAD_DIM;  // K base

    u16x8 kreg[2], vreg[2];
#define LDTILE(ktn)                                                        \
    {                                                                      \
        _Pragma("unroll") for (int p = 0; p < 2; p++) {                    \
            const unsigned short* gp =                                     \
                kvb + (size_t)((ktn) + roff[p]) * 3072 + cs8[p];           \
            kreg[p] = *(const u16x8*)gp;                                   \
            vreg[p] = *(const u16x8*)(gp + INNER);                         \
        }                                                                  \
    }

    LDTILE(qA);  // prologue
    int buf = 0;
    const int swz = (lr & 7) << 4;

    for (int half = 0; half < 2; half++) {
        const int q0 = half ? qB : qA;

        // Q fragments (B-operand layout: col=l&15, k=(l>>4)*8+j)
        const unsigned short* qbase =
            qkv + (size_t)(b * T_SEQ + q0 + wid * 16 + lr) * 3072 + h * HEAD_DIM;
        const bf16x8 qf0 = *(const bf16x8*)(qbase + lg * 8);
        const bf16x8 qf1 = *(const bf16x8*)(qbase + 32 + lg * 8);

        float mrun = -1e30f, lsum = 0.f;
        f32x4 accO[4] = {};

        for (int kt = q0; kt < T_SEQ; kt += KB) {
            // ---- write staged regs -> LDS[buf]; prefetch next tile ----
#pragma unroll
            for (int p = 0; p < 2; p++) {
                *(u16x8*)((char*)Kl[buf] + kwo[p]) = kreg[p];
                *(u16x8*)((char*)Vs[buf] + vwo[p]) = vreg[p];
            }
            const int ktn = (kt + KB < T_SEQ) ? kt + KB : (half == 0 ? qB : -1);
            if (ktn >= 0) LDTILE(ktn);
            lds_barrier();  // lgkmcnt(0)+s_barrier fused, no vmcnt drain

            // ---- S^T = K Q^T : lane holds S[key=f*16+lg*4+i][q=lr] ----
            f32x4 s[4];
#pragma unroll
            for (int f = 0; f < 4; f++) {
                const int r = f * 16 + lr;
                const int sw = ((r ^ (r >> 3)) & 7) << 4;
                bf16x8 k0 = *(const bf16x8*)((char*)Kl[buf] + r * 128 + ((lg * 16) ^ sw));
                bf16x8 k1 = *(const bf16x8*)((char*)Kl[buf] + r * 128 + ((64 + lg * 16) ^ sw));
                f32x4 z = {0.f, 0.f, 0.f, 0.f};
                z = __builtin_amdgcn_mfma_f32_16x16x32_bf16(k0, qf0, z, 0, 0, 0);
                s[f] = __builtin_amdgcn_mfma_f32_16x16x32_bf16(k1, qf1, z, 0, 0, 0);
            }

            if (kt == q0) {  // only diagonal tile can violate key>=query
                const int qg = wid * 16 + lr;  // but kg is block-local 0..63 too
                (void)qg;
#pragma unroll
                for (int f = 0; f < 4; f++)
#pragma unroll
                    for (int i = 0; i < 4; i++) {
                        const int kg = f * 16 + lg * 4 + i;
                        if (kg < (wid * 16 + lr) - (wid * 16)) {}  // placeholder
                        if (kg < lr + wid * 0) {}                   // (see below)
                    }
                // NOTE: query local index = wid*16 + lr? No -- each wave owns its
                // own 16 queries; within the 64-key tile, queries are global
                // q0 + wid*16 + lr, keys are global kt + kg. kt==q0 =>
                // mask where kg < wid*16 + lr.
#pragma unroll
                for (int f = 0; f < 4; f++)
#pragma unroll
                    for (int i = 0; i < 4; i++) {
                        const int kg = f * 16 + lg * 4 + i;
                        if (kg < wid * 16 + lr) s[f][i] = -1e30f;
                    }
            }

            // ---- online softmax, in-lane (query = lr domain) ----
            float vmax;
            {
                float m0 = fmaxf(fmaxf(s[0][0], s[0][1]), fmaxf(s[0][2], s[0][3]));
                float m1 = fmaxf(fmaxf(s[1][0], s[1][1]), fmaxf(s[1][2], s[1][3]));
                float m2 = fmaxf(fmaxf(s[2][0], s[2][1]), fmaxf(s[2][2], s[2][3]));
                float m3 = fmaxf(fmaxf(s[3][0], s[3][1]), fmaxf(s[3][2], s[3][3]));
                vmax = fmaxf(fmaxf(m0, m1), fmaxf(m2, m3));
                vmax = fmaxf(vmax, __shfl_xor(vmax, 16));
                vmax = fmaxf(vmax, __shfl_xor(vmax, 32));
            }
            if (__any(vmax > mrun + 64.f)) {   // defer-max (T13), raw-score THR
                const float mnew = fmaxf(mrun, vmax);
                const float alpha = exp2f((mrun - mnew) * cexp);
                lsum *= alpha;
                mrun = mnew;
#pragma unroll
                for (int i = 0; i < 4; i++) {
                    const float af = __shfl(alpha, lg * 4 + i);  // q-dom -> O-dom
#pragma unroll
                    for (int d = 0; d < 4; d++) accO[d][i] *= af;
                }
            }

            float rs = 0.f;
#pragma unroll
            for (int f = 0; f < 4; f++) {
                float p0 = exp2f((s[f][0] - mrun) * cexp);
                float p1 = exp2f((s[f][1] - mrun) * cexp);
                float p2 = exp2f((s[f][2] - mrun) * cexp);
                float p3 = exp2f((s[f][3] - mrun) * cexp);
                rs += (p0 + p1) + (p2 + p3);
                u32x2 pk = {cvt_pk_bf16(p0, p1), cvt_pk_bf16(p2, p3)};
                *(u32x2*)((char*)Pl[wid] + lr * 128 + ((f * 32 + lg * 8) ^ swz)) = pk;
            }
            rs += __shfl_xor(rs, 16);
            rs += __shfl_xor(rs, 32);
            lsum += rs;

            asm volatile("s_waitcnt lgkmcnt(0)" ::: "memory");  // P visible (same wave)

            // ---- O += P V  (V via hardware transpose reads) ----
            const unsigned vsb = ldsa(Vs[buf]) + lr * 8;
#pragma unroll
            for (int ks = 0; ks < 2; ks++) {
                bf16x8 pa = *(const bf16x8*)((char*)Pl[wid] + lr * 128 +
                                             ((ks * 64 + lg * 16) ^ swz));
                bf16x4 t0[4], t1[4];
#pragma unroll
                for (int df = 0; df < 4; df++)
                    tr_read2(vsb + df * 2048 + (ks * 8 + lg * 2) * 128, t0[df], t1[df]);
                asm volatile("s_waitcnt lgkmcnt(0)" ::: "memory");
                __builtin_amdgcn_sched_barrier(0);  // rule #18
#pragma unroll
                for (int df = 0; df < 4; df++) {
                    bf16x8 bv = __builtin_shufflevector(t0[df], t1[df],
                                                        0, 1, 2, 3, 4, 5, 6, 7);
                    accO[df] = __builtin_amdgcn_mfma_f32_16x16x32_bf16(
                        pa, bv, accO[df], 0, 0, 0);
                }
            }
            buf ^= 1;
        }

        // ---- normalize + store (lsum lives in q=lr domain; pull per-i) ----
        float lsq[4];
#pragma unroll
        for (int i = 0; i < 4; i++) lsq[i] = __shfl(lsum, lg * 4 + i);
#pragma unroll
        for (int df = 0; df < 4; df++)
#pragma unroll
            for (int i = 0; i < 4; i++) {
                const int row = b * T_SEQ + q0 + wid * 16 + lg * 4 + i;
                aout[(size_t)row * INNER + h * HEAD_DIM + df * 16 + lr] =
                    f2bf(accO[df][i] / lsq[i]);
            }
    }
#undef LDTILE
}

// ---------------------------------------------------------------------------
extern "C" void kernel_launch(void* const* d_in, const int* in_sizes, int n_in,
                              void* d_out, int out_size, void* d_ws, size_t ws_size,
                              hipStream_t stream) {
    const float* x     = (const float*)d_in[0];
    const float* qkv_w = (const float*)d_in[1];
    const float* qkv_b = (const float*)d_in[2];
    const float* out_w = (const float*)d_in[3];
    const float* out_b = (const float*)d_in[4];
    float* out = (float*)d_out;

    char* ws = (char*)d_ws;
    unsigned short* xb   = (unsigned short*)(ws);                  //  8 MB
    unsigned short* wqb  = (unsigned short*)(ws + (8l << 20));     //  6 MB
    unsigned short* wob  = (unsigned short*)(ws + (14l << 20));    //  2 MB
    unsigned short* qkvb = (unsigned short*)(ws + (16l << 20));    // 24 MB
    unsigned short* aob  = (unsigned short*)(ws + (40l << 20));    //  8 MB

    cvt_f32_bf16<<<4096, 256, 0, stream>>>(x, xb, TOKENS * D_MODEL);
    cvt_f32_bf16<<<3072, 256, 0, stream>>>(qkv_w, wqb, 3 * INNER * D_MODEL);
    cvt_f32_bf16<<<1024, 256, 0, stream>>>(out_w, wob, D_MODEL * INNER);

    gemm_nt<1><<<dim3(3 * INNER / 128, TOKENS / 128), 256, 0, stream>>>(
        xb, wqb, qkv_b, qkvb, TOKENS, 3 * INNER, D_MODEL);

    attn_fwd<<<dim3(16, BATCH * NHEAD), 256, 0, stream>>>(qkvb, aob);

    gemm_nt<0><<<dim3(D_MODEL / 128, TOKENS / 128), 256, 0, stream>>>(
        aob, wob, out_b, out, TOKENS, D_MODEL, INNER);
}